// Round 1
// baseline (127.994 us; speedup 1.0000x reference)
//
#include <hip/hip_runtime.h>

#define GG 16

// Pass 1: Gamma[g] = sum_e w[e] * Y[src[e]][g]
__global__ __launch_bounds__(256) void gamma_kernel(
    const float* __restrict__ Y,
    const float* __restrict__ w,
    const int* __restrict__ src,
    float* __restrict__ gamma,
    int E) {
    float acc[GG];
#pragma unroll
    for (int g = 0; g < GG; ++g) acc[g] = 0.f;

    const int stride = gridDim.x * blockDim.x;
    for (int e = blockIdx.x * blockDim.x + threadIdx.x; e < E; e += stride) {
        const int s = src[e];
        const float we = w[e];
        const float4* yrow = reinterpret_cast<const float4*>(Y + (size_t)s * GG);
#pragma unroll
        for (int q = 0; q < 4; ++q) {
            const float4 y = yrow[q];
            acc[4 * q + 0] = fmaf(we, y.x, acc[4 * q + 0]);
            acc[4 * q + 1] = fmaf(we, y.y, acc[4 * q + 1]);
            acc[4 * q + 2] = fmaf(we, y.z, acc[4 * q + 2]);
            acc[4 * q + 3] = fmaf(we, y.w, acc[4 * q + 3]);
        }
    }

    __shared__ float gs[GG];
    if (threadIdx.x < GG) gs[threadIdx.x] = 0.f;
    __syncthreads();

    const int lane = threadIdx.x & 63;
#pragma unroll
    for (int g = 0; g < GG; ++g) {
        float v = acc[g];
#pragma unroll
        for (int off = 32; off >= 1; off >>= 1) v += __shfl_down(v, off, 64);
        if (lane == 0) atomicAdd(&gs[g], v);
    }
    __syncthreads();
    if (threadIdx.x < GG) atomicAdd(&gamma[threadIdx.x], gs[threadIdx.x]);
}

// Pass 2: loss = sum_e w[e] * sum_g (Y[src[e]][g]/Gamma[g]) * (1 - Y[dst[e]][g])
__global__ __launch_bounds__(256) void loss_kernel(
    const float* __restrict__ Y,
    const float* __restrict__ w,
    const int* __restrict__ src,
    const int* __restrict__ dst,
    const float* __restrict__ gamma,
    float* __restrict__ out,
    int E) {
    float invg[GG];
#pragma unroll
    for (int g = 0; g < GG; ++g) invg[g] = 1.0f / gamma[g];  // broadcast, L2-cached

    float acc = 0.f;
    const int stride = gridDim.x * blockDim.x;
    for (int e = blockIdx.x * blockDim.x + threadIdx.x; e < E; e += stride) {
        const int s = src[e];
        const int d = dst[e];
        const float we = w[e];
        const float4* ys = reinterpret_cast<const float4*>(Y + (size_t)s * GG);
        const float4* yd = reinterpret_cast<const float4*>(Y + (size_t)d * GG);
        float dot = 0.f;
#pragma unroll
        for (int q = 0; q < 4; ++q) {
            const float4 a = ys[q];
            const float4 b = yd[q];
            dot = fmaf(a.x * invg[4 * q + 0], 1.f - b.x, dot);
            dot = fmaf(a.y * invg[4 * q + 1], 1.f - b.y, dot);
            dot = fmaf(a.z * invg[4 * q + 2], 1.f - b.z, dot);
            dot = fmaf(a.w * invg[4 * q + 3], 1.f - b.w, dot);
        }
        acc = fmaf(we, dot, acc);
    }

    // block reduce: wave shuffle -> LDS -> single atomic per block
    __shared__ float ws_red[4];
    const int lane = threadIdx.x & 63;
    const int wid = threadIdx.x >> 6;
#pragma unroll
    for (int off = 32; off >= 1; off >>= 1) acc += __shfl_down(acc, off, 64);
    if (lane == 0) ws_red[wid] = acc;
    __syncthreads();
    if (wid == 0) {
        float v = (lane < 4) ? ws_red[lane] : 0.f;
        v += __shfl_down(v, 2, 64);
        v += __shfl_down(v, 1, 64);
        if (lane == 0) atomicAdd(out, v);
    }
}

extern "C" void kernel_launch(void* const* d_in, const int* in_sizes, int n_in,
                              void* d_out, int out_size, void* d_ws, size_t ws_size,
                              hipStream_t stream) {
    const float* Y = (const float*)d_in[0];
    const float* ew = (const float*)d_in[1];
    const int* ei = (const int*)d_in[2];
    const int E = in_sizes[1];
    const int* src = ei;
    const int* dst = ei + E;

    float* gamma = (float*)d_ws;
    float* out = (float*)d_out;

    hipMemsetAsync(gamma, 0, GG * sizeof(float), stream);
    hipMemsetAsync(out, 0, sizeof(float), stream);

    gamma_kernel<<<512, 256, 0, stream>>>(Y, ew, src, gamma, E);
    loss_kernel<<<2048, 256, 0, stream>>>(Y, ew, src, dst, gamma, out, E);
}

// Round 2
// 81.229 us; speedup vs baseline: 1.5757x; 1.5757x over previous
//
#include <hip/hip_runtime.h>
#include <hip/hip_fp16.h>

#define GG 16

__device__ __forceinline__ unsigned pack2(float lo, float hi) {
    return ((unsigned)__half_as_ushort(__float2half_rn(hi)) << 16) |
           (unsigned)__half_as_ushort(__float2half_rn(lo));
}

// Convert Y (f32) -> fp16 table (3.2 MB, fits per-XCD L2). 8 floats/thread.
__global__ __launch_bounds__(256) void cvt_kernel(const float4* __restrict__ Y4,
                                                  int4* __restrict__ T4, int n8) {
    const int stride = gridDim.x * blockDim.x;
    for (int j = blockIdx.x * blockDim.x + threadIdx.x; j < n8; j += stride) {
        const float4 a = Y4[2 * j];
        const float4 b = Y4[2 * j + 1];
        int4 o;
        o.x = (int)pack2(a.x, a.y);
        o.y = (int)pack2(a.z, a.w);
        o.z = (int)pack2(b.x, b.y);
        o.w = (int)pack2(b.z, b.w);
        T4[j] = o;
    }
}

__device__ __forceinline__ void load_row_h(const __half* __restrict__ T, int node,
                                           float* out16) {
    const int4* row = reinterpret_cast<const int4*>(T + (size_t)node * GG);
    const int4 r0 = row[0];
    const int4 r1 = row[1];
    int raw[8] = {r0.x, r0.y, r0.z, r0.w, r1.x, r1.y, r1.z, r1.w};
#pragma unroll
    for (int k = 0; k < 8; ++k) {
        __half2 h = *reinterpret_cast<__half2*>(&raw[k]);
        float2 f = __half22float2(h);
        out16[2 * k] = f.x;
        out16[2 * k + 1] = f.y;
    }
}

__device__ __forceinline__ void load_row_f(const float* __restrict__ Y, int node,
                                           float* out16) {
    const float4* row = reinterpret_cast<const float4*>(Y + (size_t)node * GG);
#pragma unroll
    for (int q = 0; q < 4; ++q) {
        const float4 v = row[q];
        out16[4 * q + 0] = v.x;
        out16[4 * q + 1] = v.y;
        out16[4 * q + 2] = v.z;
        out16[4 * q + 3] = v.w;
    }
}

// Fused edge pass: accumulate Gamma[g] = sum w*Y[s][g] and S[g] = sum w*Y[s][g]*Y[d][g].
// loss = GG - sum_g S[g]/Gamma[g]  (since sum_e w*Y[s][g] == Gamma[g] exactly).
template <bool FP16>
__global__ __launch_bounds__(256) void edge_kernel(
    const float* __restrict__ Yf, const __half* __restrict__ Yh,
    const float* __restrict__ w, const int* __restrict__ src,
    const int* __restrict__ dst, float* __restrict__ acc_out, int E) {
    float gam[GG], S[GG];
#pragma unroll
    for (int g = 0; g < GG; ++g) { gam[g] = 0.f; S[g] = 0.f; }

    const int tid = blockIdx.x * blockDim.x + threadIdx.x;
    const int stride = gridDim.x * blockDim.x;
    const int E4 = E >> 2;
    const int4* s4p = reinterpret_cast<const int4*>(src);
    const int4* d4p = reinterpret_cast<const int4*>(dst);
    const float4* w4p = reinterpret_cast<const float4*>(w);

    for (int j = tid; j < E4; j += stride) {
        const int4 s4 = s4p[j];
        const int4 d4 = d4p[j];
        const float4 w4 = w4p[j];
        const int ss[4] = {s4.x, s4.y, s4.z, s4.w};
        const int dd[4] = {d4.x, d4.y, d4.z, d4.w};
        const float ww[4] = {w4.x, w4.y, w4.z, w4.w};
#pragma unroll
        for (int k = 0; k < 4; ++k) {
            float ys[GG], yd[GG];
            if constexpr (FP16) {
                load_row_h(Yh, ss[k], ys);
                load_row_h(Yh, dd[k], yd);
            } else {
                load_row_f(Yf, ss[k], ys);
                load_row_f(Yf, dd[k], yd);
            }
            const float we = ww[k];
#pragma unroll
            for (int g = 0; g < GG; ++g) {
                gam[g] = fmaf(we, ys[g], gam[g]);
                S[g] = fmaf(we, ys[g] * yd[g], S[g]);
            }
        }
    }

    // tail edges (E not divisible by 4)
    const int base = E4 << 2;
    if (base + tid < E) {
        float ys[GG], yd[GG];
        const int s = src[base + tid], d = dst[base + tid];
        if constexpr (FP16) {
            load_row_h(Yh, s, ys);
            load_row_h(Yh, d, yd);
        } else {
            load_row_f(Yf, s, ys);
            load_row_f(Yf, d, yd);
        }
        const float we = w[base + tid];
#pragma unroll
        for (int g = 0; g < GG; ++g) {
            gam[g] = fmaf(we, ys[g], gam[g]);
            S[g] = fmaf(we, ys[g] * yd[g], S[g]);
        }
    }

    // block reduce: wave shuffle -> LDS -> 32 atomics per block
    __shared__ float red[2 * GG];
    if (threadIdx.x < 2 * GG) red[threadIdx.x] = 0.f;
    __syncthreads();
    const int lane = threadIdx.x & 63;
#pragma unroll
    for (int g = 0; g < GG; ++g) {
        float v = gam[g];
        float u = S[g];
#pragma unroll
        for (int off = 32; off >= 1; off >>= 1) {
            v += __shfl_down(v, off, 64);
            u += __shfl_down(u, off, 64);
        }
        if (lane == 0) {
            atomicAdd(&red[g], v);
            atomicAdd(&red[GG + g], u);
        }
    }
    __syncthreads();
    if (threadIdx.x < 2 * GG) atomicAdd(&acc_out[threadIdx.x], red[threadIdx.x]);
}

__global__ void final_kernel(const float* __restrict__ acc, float* __restrict__ out) {
    if (threadIdx.x == 0 && blockIdx.x == 0) {
        float s = 0.f;
#pragma unroll
        for (int g = 0; g < GG; ++g) s += acc[GG + g] / acc[g];
        out[0] = (float)GG - s;
    }
}

extern "C" void kernel_launch(void* const* d_in, const int* in_sizes, int n_in,
                              void* d_out, int out_size, void* d_ws, size_t ws_size,
                              hipStream_t stream) {
    const float* Y = (const float*)d_in[0];
    const float* ew = (const float*)d_in[1];
    const int* ei = (const int*)d_in[2];
    const int NY = in_sizes[0];  // N*G elements of Y
    const int E = in_sizes[1];
    const int* src = ei;
    const int* dst = ei + E;

    float* accbuf = (float*)d_ws;  // 32 floats: gamma[16], S[16]
    const size_t tbl_off = 256;
    __half* tbl = (__half*)((char*)d_ws + tbl_off);
    const bool use_fp16 = (ws_size >= tbl_off + (size_t)NY * sizeof(__half)) && (NY % 8 == 0);

    hipMemsetAsync(d_ws, 0, 256, stream);

    if (use_fp16) {
        const int n8 = NY / 8;
        cvt_kernel<<<(n8 + 255) / 256, 256, 0, stream>>>(
            (const float4*)Y, (int4*)tbl, n8);
        edge_kernel<true><<<1536, 256, 0, stream>>>(Y, tbl, ew, src, dst, accbuf, E);
    } else {
        edge_kernel<false><<<1536, 256, 0, stream>>>(Y, (const __half*)nullptr, ew, src,
                                                     dst, accbuf, E);
    }
    final_kernel<<<1, 64, 0, stream>>>(accbuf, (float*)d_out);
}